// Round 6
// baseline (1794.248 us; speedup 1.0000x reference)
//
#include <hip/hip_runtime.h>

#define BB 16
#define NN 2048
#define PC 256
#define KK 32
#define HWS 1920
#define PT (BB*PC*KK)   // 131072 positions
#define PKr (PC*KK)     // 8192 per batch
#define EPSF 1e-5f

// d_out-resident scratch (zero d_ws usage; ws_size unknown/untrusted):
//   ch64  (per batch): idx   (int bits)    — overwritten last by k_rgb
//   ch65  (per batch): idxr  (−1 = invalid)— overwritten last by k_rgb
//   ch66  (per batch): validf at cols ≡0 mod 32 — overwritten last by k_rgb
//   (b0, ch256, cols 0..1151): BN stats    — overwritten last by k_rgb
#define CH_IDX  64
#define CH_IDXR 65
#define CH_VAL  66
#define STATS_OFF ((size_t)256*PKr)

// ---------------- Stage 1: depth-window top-K neighbor query ----------------
__global__ __launch_bounds__(256) void k_idx(
    const float* __restrict__ pc, const float* __restrict__ npc,
    const int* __restrict__ qv1, float* out)
{
  __shared__ int slots[4][KK];
  int tid = threadIdx.x;
  int wl = tid >> 6, lane = tid & 63;
  int w = blockIdx.x*4 + wl;           // 0..4095 = b*256+p
  int b = w >> 8, p = w & 255;
  if (lane == 0) slots[wl][0] = 0;     // num==0 fallback index
  float zc = npc[(b*3+2)*PC + p];
  const float* pz = pc + ((size_t)b*3+2)*NN;
  int num = 0;
  for (int ci=0; ci<NN/64; ci++) {
    int n = ci*64 + lane;
    bool m = fabsf(pz[n] - zc) < 0.5f;
    unsigned long long mk = __ballot(m);
    if (m) {
      int rank = num + __popcll(mk & ((1ull<<lane)-1ull));
      if (rank < KK) slots[wl][rank] = n;
    }
    num += __popcll(mk);
  }
  __syncthreads();
  if (lane < KK) {
    int nj = (lane < num) ? slots[wl][lane] : slots[wl][0];
    size_t col = (size_t)p*KK + lane;
    ((int*)out)[((size_t)b*640 + CH_IDX )*PKr + col] = nj;
    ((int*)out)[((size_t)b*640 + CH_IDXR)*PKr + col] = (num > 0) ? qv1[b*NN + nj] : -1;
  }
  if (lane == 0)
    out[((size_t)b*640 + CH_VAL)*PKr + (size_t)p*KK] = (num > 0) ? 1.0f : 0.0f;
}

// ---------------- Stage 2: zero the BN stats accumulators ----------------
__global__ __launch_bounds__(256) void k_zero(float* out)
{
  int i = blockIdx.x*256 + threadIdx.x;
  if (i < 1152) out[STATS_OFF + i] = 0.0f;
}

// ---- shared conv core: y = W*x (raw, pre-BN) -> f32 store + global stats --
template<int CIN, int COUT>
__device__ __forceinline__ void conv_core(
    const float* __restrict__ x, const float* __restrict__ wf,
    float* ybase, size_t base0, size_t ostride,
    float* lsum, float* lsq, int tid)
{
  for (int o=0;o<COUT;o++) {
    const float* wr = wf + o*CIN;
    float a0=0.f,a1=0.f,a2=0.f,a3=0.f;
    constexpr int C4 = (CIN/4)*4;
    #pragma unroll
    for (int c=0;c<C4;c+=4) {
      a0 = fmaf(wr[c+0], x[c+0], a0);
      a1 = fmaf(wr[c+1], x[c+1], a1);
      a2 = fmaf(wr[c+2], x[c+2], a2);
      a3 = fmaf(wr[c+3], x[c+3], a3);
    }
    #pragma unroll
    for (int c=C4;c<CIN;c++) a0 = fmaf(wr[c], x[c], a0);
    float acc = (a0+a1)+(a2+a3);
    ybase[base0 + (size_t)o*ostride] = acc;
    float s = acc, q = acc*acc;
    #pragma unroll
    for (int off=32; off>0; off>>=1) { s += __shfl_down(s, off); q += __shfl_down(q, off); }
    if ((tid & 63) == 0) { atomicAdd(&lsum[o], s); atomicAdd(&lsq[o], q); }
  }
}

// ---------------- Stage 3: gather + conv1 -> raw y1 in out ch 0..63 --------
__global__ __launch_bounds__(256) void k_conv1(
    const float* __restrict__ pc, const float* __restrict__ npc,
    const float* __restrict__ feat,
    const float* __restrict__ wf, float* out)
{
  __shared__ float lsum[64], lsq[64];
  int tid = threadIdx.x;
  if (tid < 64) { lsum[tid]=0.f; lsq[tid]=0.f; }
  __syncthreads();
  int pos = blockIdx.x*256 + tid;
  int b = pos >> 13, rem = pos & 8191, p = rem >> 5;
  int n = ((const int*)out)[((size_t)b*640 + CH_IDX)*PKr + rem];
  float x[67];
  #pragma unroll
  for (int ch=0; ch<3; ch++)
    x[ch] = pc[((size_t)b*3+ch)*NN + n] - npc[(b*3+ch)*PC + p];
  #pragma unroll
  for (int c=0;c<64;c++) x[3+c] = feat[((size_t)b*64+c)*NN + n];
  size_t obase = (size_t)b*640*PKr + rem;   // out channel base 0
  conv_core<67,64>(x, wf, out, obase, PKr, lsum, lsq, tid);
  __syncthreads();
  float* st1 = out + STATS_OFF;             // cols 0..127
  if (tid < 64) { atomicAdd(&st1[tid], lsum[tid]); atomicAdd(&st1[64+tid], lsq[tid]); }
}

// -------- Stages 4-6: normalize prev (in out, in place) + conv -------------
// Raw y read from out channels [IN_BASE, IN_BASE+CIN); if WB, normalized*valid
// written back in place. Raw conv output written to [OUT_BASE, OUT_BASE+COUT).
// conv4 uses IN_BASE==OUT_BASE==384: safe — each (ch,pos) column is owned by
// exactly one thread, which loads all CIN inputs into registers before
// conv_core's first store (same-pointer aliasing preserves order).
template<int CIN, int COUT, int IN_BASE, int OUT_BASE, bool WB, int ST_IN, int ST_OUT>
__global__ __launch_bounds__(256) void k_conv(
    const float* __restrict__ g, const float* __restrict__ bbv,
    const float* __restrict__ wf, float* out)
{
  __shared__ float sc[CIN], sh[CIN], lsum[COUT], lsq[COUT];
  int tid = threadIdx.x;
  const float* stin = out + STATS_OFF + ST_IN;
  if (tid < CIN) {
    float m   = stin[tid] * (1.0f/PT);
    float var = stin[CIN+tid] * (1.0f/PT) - m*m;
    float inv = rsqrtf(var + EPSF);
    float s = inv * g[tid];
    sc[tid] = s; sh[tid] = bbv[tid] - m*s;
  }
  if (tid < COUT) { lsum[tid]=0.f; lsq[tid]=0.f; }
  __syncthreads();
  int pos = blockIdx.x*256 + tid;
  int b = pos >> 13, rem = pos & 8191;
  size_t ibase = ((size_t)b*640 + IN_BASE)*PKr + rem;
  float x[CIN];
  #pragma unroll
  for (int c=0;c<CIN;c++)
    x[c] = fmaxf(fmaf(out[ibase + (size_t)c*PKr], sc[c], sh[c]), 0.0f);
  if constexpr (WB) {
    float v = out[((size_t)b*640 + CH_VAL)*PKr + (rem & ~31)];
    #pragma unroll
    for (int c=0;c<CIN;c++) out[ibase + (size_t)c*PKr] = x[c]*v;
  }
  size_t obase = ((size_t)b*640 + OUT_BASE)*PKr + rem;
  conv_core<CIN,COUT>(x, wf, out, obase, PKr, lsum, lsq, tid);
  __syncthreads();
  float* stout = out + STATS_OFF + ST_OUT;
  if (tid < COUT) { atomicAdd(&stout[tid], lsum[tid]); atomicAdd(&stout[COUT+tid], lsq[tid]); }
}

// ------- Stage 7: normalize y4 in place in out ch 384..639, apply valid ----
__global__ __launch_bounds__(256) void k_out4(
    const float* __restrict__ g, const float* __restrict__ bbv, float* out)
{
  __shared__ float sc[256], sh[256];
  int tid = threadIdx.x;
  {
    const float* st4 = out + STATS_OFF + 640;
    float m   = st4[tid] * (1.0f/PT);
    float var = st4[256+tid]*(1.0f/PT) - m*m;
    float inv = rsqrtf(var + EPSF);
    float s = inv * g[tid];
    sc[tid] = s; sh[tid] = bbv[tid] - m*s;
  }
  __syncthreads();
  int pos = blockIdx.x*256 + tid;
  int b = pos >> 13, rem = pos & 8191;
  float v = out[((size_t)b*640 + CH_VAL)*PKr + (rem & ~31)];
  size_t obase = ((size_t)b*640 + 384)*PKr + rem;
  #pragma unroll 8
  for (int c=0;c<256;c++) {
    float yv = out[obase + (size_t)c*PKr];
    out[obase + (size_t)c*PKr] = fmaxf(fmaf(yv, sc[c], sh[c]), 0.0f) * v;
  }
}

// ---------------- Stage 8: rgb gathers -> out ch 64..127 and 256..383 ------
// Runs LAST; overwrites the scratch channels (64..66, 256). Each thread reads
// only its own column's idxr before writing its own column — race-free.
__global__ __launch_bounds__(256) void k_rgb(
    const float* __restrict__ img1, const float* __restrict__ img2, float* out)
{
  int tid = threadIdx.x;
  int pos = blockIdx.x*256 + tid;
  int b = pos >> 13, rem = pos & 8191;
  int enc = ((const int*)out)[((size_t)b*640 + CH_IDXR)*PKr + rem];
  float v  = (enc >= 0) ? 1.0f : 0.0f;
  int  ir  = (enc >= 0) ? enc : 0;
  size_t o1 = ((size_t)b*640 + 64)*PKr + rem;
  const float* i1 = img1 + (size_t)b*64*HWS + ir;
  #pragma unroll 8
  for (int c=0;c<64;c++) out[o1 + (size_t)c*PKr] = i1[(size_t)c*HWS] * v;
  size_t o2 = ((size_t)b*640 + 256)*PKr + rem;
  const float* i2 = img2 + (size_t)b*128*HWS + ir;
  #pragma unroll 8
  for (int c=0;c<128;c++) out[o2 + (size_t)c*PKr] = i2[(size_t)c*HWS] * v;
}

extern "C" void kernel_launch(void* const* d_in, const int* in_sizes, int n_in,
                              void* d_out, int out_size, void* d_ws, size_t ws_size,
                              hipStream_t stream)
{
  const float* pc   = (const float*)d_in[0];
  const float* feat = (const float*)d_in[1];
  const float* img1 = (const float*)d_in[2];
  const float* img2 = (const float*)d_in[3];
  // d_in[4] = P (unused by reference)
  const int*   qv1  = (const int*)d_in[5];
  const float* npc  = (const float*)d_in[6];
  const float* w1 = (const float*)d_in[7];
  const float* g1 = (const float*)d_in[8];
  const float* b1 = (const float*)d_in[9];
  const float* w2 = (const float*)d_in[10];
  const float* g2 = (const float*)d_in[11];
  const float* b2 = (const float*)d_in[12];
  const float* w3 = (const float*)d_in[13];
  const float* g3 = (const float*)d_in[14];
  const float* b3 = (const float*)d_in[15];
  const float* w4 = (const float*)d_in[16];
  const float* g4 = (const float*)d_in[17];
  const float* b4 = (const float*)d_in[18];
  float* out = (float*)d_out;
  (void)d_ws; (void)ws_size;   // deliberately unused — all scratch is in d_out

  // d_out layout during pipeline (final content in parens):
  //   ch0..63:    raw y1 -> pf1*valid (conv2 WB)
  //   ch64..65:   idx / idxr scratch  (rgb1 via k_rgb, last)
  //   ch66:       validf scratch      (rgb1 via k_rgb, last)
  //   ch128..255: raw y2 -> pf2*valid (conv3 WB)
  //   b0 ch256 cols0..1151: BN stats  (rgb2 via k_rgb, last)
  //   ch384..511: raw y3 (conv3) -> overwritten by raw y4 (conv4)
  //   ch384..639: raw y4 -> pf4*valid (k_out4)

  k_idx  <<<1024,256,0,stream>>>(pc, npc, qv1, out);
  k_zero <<<5,   256,0,stream>>>(out);
  // conv1: gathered input -> raw y1 in out ch 0..63; stats at cols 0..127
  k_conv1<<<512, 256,0,stream>>>(pc, npc, feat, w1, out);
  // conv2: norm y1 (in place, *valid) -> raw y2 in ch 128..255; st 128..383
  k_conv<64,128,0,128,true,0,128>     <<<512,256,0,stream>>>(g1, b1, w2, out);
  // conv3: norm y2 (in place, *valid) -> raw y3 in ch 384..511; st 384..639
  k_conv<128,128,128,384,true,128,384><<<512,256,0,stream>>>(g2, b2, w3, out);
  // conv4: norm y3 (ch384..511) -> raw y4 in ch 384..639; st 640..1151
  k_conv<128,256,384,384,false,384,640><<<512,256,0,stream>>>(g3, b3, w4, out);
  // normalize y4 in place, apply valid
  k_out4 <<<512,256,0,stream>>>(g4, b4, out);
  // rgb gathers (overwrites all scratch channels)
  k_rgb  <<<512,256,0,stream>>>(img1, img2, out);
}

// Round 7
// 1279.481 us; speedup vs baseline: 1.4023x; 1.4023x over previous
//
#include <hip/hip_runtime.h>

#define BB 16
#define NN 2048
#define PC 256
#define KK 32
#define HWS 1920
#define PT (BB*PC*KK)   // 131072 positions
#define PKr (PC*KK)     // 8192 per batch
#define EPSF 1e-5f

// d_out-resident scratch (zero d_ws usage):
//  ch0..63   : raw y1 f32  (conv1 out; conv2 X; k_norm1 in-place -> pf1*valid)
//  ch64..127 : raw y3 bf16-packed pairs (conv3 out; conv4 X); k_rgb overwrites last
//  ch128..255: raw y2 f32  (conv2 out; conv3 X; k_norm2 in-place -> pf2*valid)
//  ch256     : idxr (-1 = invalid)   } per-batch, finalized by k_rgb (rgb2)
//  ch257     : idx                   }
//  ch258     : valid at cols ≡0 mod 32
//  ch259(b0) : BN stats cols 0..1151
//  ch384..639: raw y4 f32 (conv4 out; k_out4 in-place -> pf4*valid)
#define CH_IDXR 256
#define CH_IDX  257
#define CH_VAL  258
#define STATS_OFF ((size_t)259 << 13)

__device__ __forceinline__ unsigned bfpack(float a, float b) {
  unsigned ua = __float_as_uint(a); ua = (ua + 0x7FFFu + ((ua >> 16) & 1u)) >> 16;
  unsigned ub = __float_as_uint(b); ub = (ub + 0x7FFFu + ((ub >> 16) & 1u)) >> 16;
  return ua | (ub << 16);
}

// ---------------- Stage 1: depth-window top-K neighbor query ----------------
__global__ __launch_bounds__(256) void k_idx(
    const float* __restrict__ pc, const float* __restrict__ npc,
    const int* __restrict__ qv1, float* out)
{
  __shared__ int slots[4][KK];
  int tid = threadIdx.x;
  int wl = tid >> 6, lane = tid & 63;
  int w = blockIdx.x*4 + wl;           // 0..4095 = b*256+p
  int b = w >> 8, p = w & 255;
  if (lane == 0) slots[wl][0] = 0;     // num==0 fallback index
  float zc = npc[(b*3+2)*PC + p];
  const float* pz = pc + ((size_t)b*3+2)*NN;
  int num = 0;
  for (int ci=0; ci<NN/64; ci++) {
    int n = ci*64 + lane;
    bool m = fabsf(pz[n] - zc) < 0.5f;
    unsigned long long mk = __ballot(m);
    if (m) {
      int rank = num + __popcll(mk & ((1ull<<lane)-1ull));
      if (rank < KK) slots[wl][rank] = n;
    }
    num += __popcll(mk);
  }
  __syncthreads();
  if (lane < KK) {
    int nj = (lane < num) ? slots[wl][lane] : slots[wl][0];
    size_t col = (size_t)p*KK + lane;
    ((int*)out)[(((size_t)b*640 + CH_IDX )<<13) + col] = nj;
    ((int*)out)[(((size_t)b*640 + CH_IDXR)<<13) + col] = (num > 0) ? qv1[b*NN + nj] : -1;
  }
  if (lane == 0)
    out[(((size_t)b*640 + CH_VAL)<<13) + (size_t)p*KK] = (num > 0) ? 1.0f : 0.0f;
}

// ---------------- Stage 2: zero the BN stats accumulators ----------------
__global__ __launch_bounds__(256) void k_zero(float* out)
{
  int i = blockIdx.x*256 + threadIdx.x;
  if (i < 1152) out[STATS_OFF + i] = 0.0f;
}

// ---------------- Tiled GEMM: Y[o,pos] = sum_c W[o,c] * X[c,pos] ------------
// Tile: 64 och x 128 pos per 256-thread block; thread = 4 och x 8 pos.
// XMODE: 0 = gather (conv1, no norm), 1 = f32 channels + norm+relu,
//        2 = packed-bf16 channels + norm+relu.
// YMODE: 0 = f32 channel write, 1 = bf16 pair-packed write (ch YBASE+q).
template<int CIN, int CINP, int COUT, int XBASE, int YBASE,
         int STIN, int STOUT, int XMODE, int YMODE>
__global__ __launch_bounds__(256,2) void k_gemm(
    const float* __restrict__ pc, const float* __restrict__ npc,
    const float* __restrict__ feat, const float* __restrict__ W,
    const float* __restrict__ g, const float* __restrict__ bv,
    float* out)
{
  __shared__ float wlds[CINP][68];     // [c][och], stride 68 keeps 16B align
  __shared__ float xlds[32][132];      // [c-chunk][pos]
  __shared__ float scs[128], shs[128];
  int tid = threadIdx.x;
  int tx = tid & 15, ty = tid >> 4;
  int ptile = blockIdx.x;              // 1024 = 16 b x 64 tiles
  int b = ptile >> 6;
  int col0 = (ptile & 63) << 7;
  int och0 = blockIdx.y << 6;

  for (int i = tid; i < 64*CIN; i += 256) {
    int o = i / CIN, c = i - o*CIN;
    wlds[c][o] = W[(size_t)(och0 + o)*CIN + c];
  }
  if constexpr (CINP > CIN) {
    for (int i = tid; i < (CINP-CIN)*64; i += 256)
      wlds[CIN + i/64][i & 63] = 0.f;
  }
  if constexpr (XMODE != 0) {
    const float* stin = out + STATS_OFF + STIN;
    for (int c = tid; c < CIN; c += 256) {
      float m   = stin[c] * (1.0f/PT);
      float var = stin[CIN+c]*(1.0f/PT) - m*m;
      float s = rsqrtf(var + EPSF) * g[c];
      scs[c] = s; shs[c] = bv[c] - m*s;
    }
  }
  __syncthreads();

  float acc[4][8];
  #pragma unroll
  for (int i=0;i<4;i++)
    #pragma unroll
    for (int j=0;j<8;j++) acc[i][j] = 0.f;

  for (int ck = 0; ck < CINP; ck += 32) {
    if constexpr (XMODE == 0) {
      #pragma unroll
      for (int k = 0; k < 16; k++) {
        int e = tid + k*256;           // 4096 elements
        int r = e >> 7, cc = e & 127;
        int c = ck + r, col = col0 + cc;
        float v = 0.f;
        if (c < CIN) {
          int n = ((const int*)out)[(((size_t)b*640 + CH_IDX)<<13) + col];
          if (c < 3) v = pc[((size_t)b*3+c)*NN + n] - npc[(b*3+c)*PC + (col>>5)];
          else       v = feat[((size_t)b*64 + (c-3))*NN + n];
        }
        xlds[r][cc] = v;
      }
    } else if constexpr (XMODE == 1) {
      #pragma unroll
      for (int k = 0; k < 4; k++) {
        int e = tid + k*256;           // 1024 float4s
        int r = e >> 5, cg = e & 31;
        int c = ck + r;
        float4 vv = *(const float4*)&out[(((size_t)b*640 + XBASE + c)<<13) + col0 + cg*4];
        float4 o4;
        o4.x = fmaxf(fmaf(vv.x, scs[c], shs[c]), 0.f);
        o4.y = fmaxf(fmaf(vv.y, scs[c], shs[c]), 0.f);
        o4.z = fmaxf(fmaf(vv.z, scs[c], shs[c]), 0.f);
        o4.w = fmaxf(fmaf(vv.w, scs[c], shs[c]), 0.f);
        *(float4*)&xlds[r][cg*4] = o4;
      }
    } else {
      #pragma unroll
      for (int k = 0; k < 2; k++) {
        int e = tid + k*256;           // 512 uint4s
        int q = e >> 5, cg = e & 31;   // q: local packed row 0..15
        int qg = (ck >> 1) + q;
        uint4 uv = *(const uint4*)&((const unsigned*)out)[(((size_t)b*640 + XBASE + qg)<<13) + col0 + cg*4];
        int c0 = ck + 2*q, c1 = c0 + 1;
        float4 lo4, hi4;
        lo4.x = fmaxf(fmaf(__uint_as_float(uv.x << 16),          scs[c0], shs[c0]), 0.f);
        lo4.y = fmaxf(fmaf(__uint_as_float(uv.y << 16),          scs[c0], shs[c0]), 0.f);
        lo4.z = fmaxf(fmaf(__uint_as_float(uv.z << 16),          scs[c0], shs[c0]), 0.f);
        lo4.w = fmaxf(fmaf(__uint_as_float(uv.w << 16),          scs[c0], shs[c0]), 0.f);
        hi4.x = fmaxf(fmaf(__uint_as_float(uv.x & 0xffff0000u),  scs[c1], shs[c1]), 0.f);
        hi4.y = fmaxf(fmaf(__uint_as_float(uv.y & 0xffff0000u),  scs[c1], shs[c1]), 0.f);
        hi4.z = fmaxf(fmaf(__uint_as_float(uv.z & 0xffff0000u),  scs[c1], shs[c1]), 0.f);
        hi4.w = fmaxf(fmaf(__uint_as_float(uv.w & 0xffff0000u),  scs[c1], shs[c1]), 0.f);
        *(float4*)&xlds[2*q  ][cg*4] = lo4;
        *(float4*)&xlds[2*q+1][cg*4] = hi4;
      }
    }
    __syncthreads();

    #pragma unroll 8
    for (int r = 0; r < 32; r++) {
      float4 wv = *(float4*)&wlds[ck + r][ty*4];
      float4 xa = *(float4*)&xlds[r][tx*4];
      float4 xb = *(float4*)&xlds[r][64 + tx*4];
      float wr[4] = {wv.x, wv.y, wv.z, wv.w};
      float xr[8] = {xa.x, xa.y, xa.z, xa.w, xb.x, xb.y, xb.z, xb.w};
      #pragma unroll
      for (int i=0;i<4;i++)
        #pragma unroll
        for (int j=0;j<8;j++) acc[i][j] = fmaf(wr[i], xr[j], acc[i][j]);
    }
    __syncthreads();
  }

  // stats: reduce over the 128 pos of this block, one atomic per och
  float* stg = out + STATS_OFF + STOUT;
  #pragma unroll
  for (int i = 0; i < 4; i++) {
    int och = och0 + ty*4 + i;
    float s = 0.f, q = 0.f;
    #pragma unroll
    for (int j = 0; j < 8; j++) { s += acc[i][j]; q += acc[i][j]*acc[i][j]; }
    s += __shfl_down(s, 8, 16); q += __shfl_down(q, 8, 16);
    s += __shfl_down(s, 4, 16); q += __shfl_down(q, 4, 16);
    s += __shfl_down(s, 2, 16); q += __shfl_down(q, 2, 16);
    s += __shfl_down(s, 1, 16); q += __shfl_down(q, 1, 16);
    if (tx == 0) { atomicAdd(&stg[och], s); atomicAdd(&stg[COUT + och], q); }
  }

  if constexpr (YMODE == 0) {
    #pragma unroll
    for (int i = 0; i < 4; i++) {
      size_t basep = (((size_t)b*640 + YBASE + och0 + ty*4 + i)<<13) + col0;
      float4 v0 = {acc[i][0], acc[i][1], acc[i][2], acc[i][3]};
      float4 v1 = {acc[i][4], acc[i][5], acc[i][6], acc[i][7]};
      *(float4*)&out[basep + tx*4]      = v0;
      *(float4*)&out[basep + 64 + tx*4] = v1;
    }
  } else {
    #pragma unroll
    for (int qi = 0; qi < 2; qi++) {
      int qg = (och0 >> 1) + ty*2 + qi;
      int a = 2*qi, c = 2*qi+1;
      uint4 u0, u1;
      u0.x = bfpack(acc[a][0], acc[c][0]); u0.y = bfpack(acc[a][1], acc[c][1]);
      u0.z = bfpack(acc[a][2], acc[c][2]); u0.w = bfpack(acc[a][3], acc[c][3]);
      u1.x = bfpack(acc[a][4], acc[c][4]); u1.y = bfpack(acc[a][5], acc[c][5]);
      u1.z = bfpack(acc[a][6], acc[c][6]); u1.w = bfpack(acc[a][7], acc[c][7]);
      size_t basep = (((size_t)b*640 + YBASE + qg)<<13) + col0;
      *(uint4*)&((unsigned*)out)[basep + tx*4]      = u0;
      *(uint4*)&((unsigned*)out)[basep + 64 + tx*4] = u1;
    }
  }
}

// ---- in-place normalize: out[CH0..CH0+CIN) = relu(norm(raw y)) * valid ----
template<int CH0, int CIN, int ST>
__global__ __launch_bounds__(256) void k_norm(
    const float* __restrict__ g, const float* __restrict__ bv, float* out)
{
  __shared__ float sc[256], sh[256];
  int tid = threadIdx.x;
  const float* stin = out + STATS_OFF + ST;
  if (tid < CIN) {
    float m   = stin[tid] * (1.0f/PT);
    float var = stin[CIN+tid]*(1.0f/PT) - m*m;
    float s = rsqrtf(var + EPSF) * g[tid];
    sc[tid] = s; sh[tid] = bv[tid] - m*s;
  }
  __syncthreads();
  int pos = blockIdx.x*256 + tid;
  int b = pos >> 13, rem = pos & 8191;
  float v = out[(((size_t)b*640 + CH_VAL)<<13) + (rem & ~31)];
  size_t base = (((size_t)b*640 + CH0)<<13) + rem;
  #pragma unroll 8
  for (int c = 0; c < CIN; c++) {
    float yv = out[base + ((size_t)c<<13)];
    out[base + ((size_t)c<<13)] = fmaxf(fmaf(yv, sc[c], sh[c]), 0.0f) * v;
  }
}

// ---------------- rgb gathers -> out ch 64..127 and 256..383 (LAST) --------
__global__ __launch_bounds__(256) void k_rgb(
    const float* __restrict__ img1, const float* __restrict__ img2, float* out)
{
  int tid = threadIdx.x;
  int pos = blockIdx.x*256 + tid;
  int b = pos >> 13, rem = pos & 8191;
  int enc = ((const int*)out)[(((size_t)b*640 + CH_IDXR)<<13) + rem];
  float v  = (enc >= 0) ? 1.0f : 0.0f;
  int  ir  = (enc >= 0) ? enc : 0;
  size_t o1 = (((size_t)b*640 + 64)<<13) + rem;
  const float* i1 = img1 + (size_t)b*64*HWS + ir;
  #pragma unroll 8
  for (int c=0;c<64;c++) out[o1 + ((size_t)c<<13)] = i1[(size_t)c*HWS] * v;
  size_t o2 = (((size_t)b*640 + 256)<<13) + rem;
  const float* i2 = img2 + (size_t)b*128*HWS + ir;
  #pragma unroll 8
  for (int c=0;c<128;c++) out[o2 + ((size_t)c<<13)] = i2[(size_t)c*HWS] * v;
}

extern "C" void kernel_launch(void* const* d_in, const int* in_sizes, int n_in,
                              void* d_out, int out_size, void* d_ws, size_t ws_size,
                              hipStream_t stream)
{
  const float* pc   = (const float*)d_in[0];
  const float* feat = (const float*)d_in[1];
  const float* img1 = (const float*)d_in[2];
  const float* img2 = (const float*)d_in[3];
  // d_in[4] = P (unused by reference)
  const int*   qv1  = (const int*)d_in[5];
  const float* npc  = (const float*)d_in[6];
  const float* w1 = (const float*)d_in[7];
  const float* g1 = (const float*)d_in[8];
  const float* b1 = (const float*)d_in[9];
  const float* w2 = (const float*)d_in[10];
  const float* g2 = (const float*)d_in[11];
  const float* b2 = (const float*)d_in[12];
  const float* w3 = (const float*)d_in[13];
  const float* g3 = (const float*)d_in[14];
  const float* b3 = (const float*)d_in[15];
  const float* w4 = (const float*)d_in[16];
  const float* g4 = (const float*)d_in[17];
  const float* b4 = (const float*)d_in[18];
  float* out = (float*)d_out;
  (void)d_ws; (void)ws_size;   // all scratch lives in d_out

  k_idx  <<<1024,256,0,stream>>>(pc, npc, qv1, out);
  k_zero <<<5,   256,0,stream>>>(out);
  // conv1: gathered X -> raw y1 f32 in ch0..63; st1 at stats+0
  k_gemm<67,96,64, 0,0,  -1,  0, 0,0><<<dim3(1024,1),256,0,stream>>>(pc,npc,feat,w1,g1,b1,out);
  // conv2: X = norm(y1) ch0..63 -> raw y2 f32 in ch128..255; st2 at +128
  k_gemm<64,64,128, 0,128, 0,128, 1,0><<<dim3(1024,2),256,0,stream>>>(pc,npc,feat,w2,g1,b1,out);
  // norm1: ch0..63 in place -> pf1*valid (after conv2 consumed raw y1)
  k_norm<0,64,0><<<512,256,0,stream>>>(g1,b1,out);
  // conv3: X = norm(y2) ch128..255 -> raw y3 bf16-packed in ch64..127; st3 at +384
  k_gemm<128,128,128, 128,64, 128,384, 1,1><<<dim3(1024,2),256,0,stream>>>(pc,npc,feat,w3,g2,b2,out);
  // norm2: ch128..255 in place -> pf2*valid
  k_norm<128,128,128><<<512,256,0,stream>>>(g2,b2,out);
  // conv4: X = norm(y3) packed ch64..127 -> raw y4 f32 in ch384..639; st4 at +640
  k_gemm<128,128,256, 64,384, 384,640, 2,0><<<dim3(1024,4),256,0,stream>>>(pc,npc,feat,w4,g3,b3,out);
  // out4: ch384..639 in place -> pf4*valid
  k_norm<384,256,640><<<512,256,0,stream>>>(g4,b4,out);
  // rgb gathers (overwrite ch64..127 and 256..383 incl. all small scratch)
  k_rgb  <<<512,256,0,stream>>>(img1, img2, out);
}